// Round 6
// baseline (632.277 us; speedup 1.0000x reference)
//
#include <hip/hip_runtime.h>
#include <math.h>

#define H_HEADS 8
#define C_DIM   32
#define HC      256
#define F_IN    512
#define NEG_SLOPE 0.2f

typedef __attribute__((ext_vector_type(8))) short    bf16x8;
typedef __attribute__((ext_vector_type(4))) short    s16x4;
typedef __attribute__((ext_vector_type(4))) float    f32x4;
typedef __attribute__((ext_vector_type(2))) float    f32x2;
typedef __attribute__((ext_vector_type(8))) _Float16 h16x8;

__device__ __forceinline__ short f2bf(float f) {
    union { float f; unsigned u; } v; v.f = f;
    unsigned r = v.u + 0x7FFF + ((v.u >> 16) & 1);   // RNE
    return (short)(r >> 16);
}

__device__ __forceinline__ void gl2lds16(const short* g, short* l) {
    __builtin_amdgcn_global_load_lds(
        (const __attribute__((address_space(1))) void*)g,
        (__attribute__((address_space(3))) void*)l, 16, 0, 0);
}

// ---------------------------------------------------------------------------
// Repack W [K,256] fp32 -> MFMA B-frag-ordered bf16 (16 KB per K-step of 32).
// ---------------------------------------------------------------------------
__global__ void wfrag_kernel(const float* __restrict__ W, short* __restrict__ Wf, int K)
{
    int tid = blockIdx.x * 256 + threadIdx.x;
    if (tid >= K * HC) return;
    int j  = tid & 7;
    int l  = (tid >> 3) & 63;
    int nb = (tid >> 9) & 15;
    int s  = tid >> 13;
    int k  = s * 32 + (l >> 4) * 8 + j;
    int n  = nb * 16 + (l & 15);
    Wf[tid] = f2bf(W[(size_t)k * HC + n]);
}

// ---------------------------------------------------------------------------
// Layer-1 MFMA GEMM (A fp32, K=512). 64-row x 256-col tile, 4 waves.
// B LDS double-buffer (2x16KB, exactly 32 KB); A prefetched TWO steps deep so
// the per-step barrier's vmcnt(0) drain never exposes HBM latency for A.
// Fused epilogue: h8 (fp8 e4m3) + per-head alpha dots (alpha LDS aliased
// into the dead B buffer).
// ---------------------------------------------------------------------------
__global__ __launch_bounds__(256, 4) void gemm1_mfma(const float* __restrict__ A32,
    const short* __restrict__ Bf, unsigned char* __restrict__ h8,
    const float* __restrict__ a_s, const float* __restrict__ a_d,
    float* __restrict__ alpha_s, float* __restrict__ alpha_d, int M)
{
    __shared__ short Bs[2][8192];            // 32 KB exactly

    const int tid  = threadIdx.x;
    const int w    = tid >> 6;
    const int lane = tid & 63;
    const int quad = lane >> 4;
    const int ml   = lane & 15;
    const int bm   = blockIdx.x * 64;

    const int rowA = bm + w * 16 + ml;
    const int rowL = rowA < M ? rowA : M - 1;

    f32x4 acc[16];
    #pragma unroll
    for (int nb = 0; nb < 16; ++nb) acc[nb] = (f32x4){0.f, 0.f, 0.f, 0.f};

    const int nsteps = F_IN >> 5;            // 16

    {   // stage B step 0
        const short* g = Bf + (size_t)w * 2048 + lane * 8;
        short* l = &Bs[0][w * 2048];
        #pragma unroll
        for (int c = 0; c < 4; ++c) gl2lds16(g + c * 512, l + c * 512);
    }

    // 2-deep A prefetch
    const float* abase = A32 + (size_t)rowL * F_IN + quad * 8;
    float4 pa[2][2];
    pa[0][0] = *(const float4*)(abase);
    pa[0][1] = *(const float4*)(abase + 4);
    pa[1][0] = *(const float4*)(abase + 32);
    pa[1][1] = *(const float4*)(abase + 36);

    for (int s = 0; s < nsteps; ++s) {
        __syncthreads();

        if (s + 1 < nsteps) {
            const short* g = Bf + (size_t)(s + 1) * 8192 + w * 2048 + lane * 8;
            short* l = &Bs[(s + 1) & 1][w * 2048];
            #pragma unroll
            for (int c = 0; c < 4; ++c) gl2lds16(g + c * 512, l + c * 512);
        }

        bf16x8 af;
        {
            float4 q0 = pa[s & 1][0], q1 = pa[s & 1][1];
            af[0] = f2bf(q0.x); af[1] = f2bf(q0.y); af[2] = f2bf(q0.z); af[3] = f2bf(q0.w);
            af[4] = f2bf(q1.x); af[5] = f2bf(q1.y); af[6] = f2bf(q1.z); af[7] = f2bf(q1.w);
        }
        if (s + 2 < nsteps) {
            pa[s & 1][0] = *(const float4*)(abase + (s + 2) * 32);
            pa[s & 1][1] = *(const float4*)(abase + (s + 2) * 32 + 4);
        }

        const short* bsrc = &Bs[s & 1][lane * 8];
        #pragma unroll
        for (int nb = 0; nb < 16; ++nb) {
            bf16x8 bfr = *(const bf16x8*)(bsrc + nb * 512);
            acc[nb] = __builtin_amdgcn_mfma_f32_16x16x32_bf16(af, bfr, acc[nb], 0, 0, 0);
        }
    }

    // ---- epilogue: fp8 store + fused per-head alpha dots ----
    float as_v[16], ad_v[16];
    #pragma unroll
    for (int nb = 0; nb < 16; ++nb) {
        as_v[nb] = a_s[nb * 16 + ml];
        ad_v[nb] = a_d[nb * 16 + ml];
    }

    __syncthreads();                          // B buffers dead; alias for alpha
    float* Als = (float*)&Bs[0][0];           // 512 f32
    float* Ald = Als + 512;                   // 512 f32

    #pragma unroll
    for (int r = 0; r < 4; ++r) {
        const int rl  = w * 16 + quad * 4 + r;
        const int row = bm + rl;

        if (row < M) {
            unsigned char* hrow = h8 + (size_t)row * HC;
            #pragma unroll
            for (int i = 0; i < 8; ++i) {
                int pk = __builtin_amdgcn_cvt_pk_fp8_f32(acc[2 * i][r], acc[2 * i + 1][r], 0, false);
                hrow[(2 * i) * 16 + ml]     = (unsigned char)(pk & 0xFF);
                hrow[(2 * i + 1) * 16 + ml] = (unsigned char)((pk >> 8) & 0xFF);
            }
        }

        float hs[8], hd[8];
        #pragma unroll
        for (int q = 0; q < 8; ++q) {
            hs[q] = acc[2 * q][r] * as_v[2 * q] + acc[2 * q + 1][r] * as_v[2 * q + 1];
            hd[q] = acc[2 * q][r] * ad_v[2 * q] + acc[2 * q + 1][r] * ad_v[2 * q + 1];
        }
        #pragma unroll
        for (int off = 1; off < 16; off <<= 1) {
            #pragma unroll
            for (int q = 0; q < 8; ++q) {
                hs[q] += __shfl_xor(hs[q], off);
                hd[q] += __shfl_xor(hd[q], off);
            }
        }
        if (ml == 0) {
            #pragma unroll
            for (int q = 0; q < 8; ++q) {
                Als[rl * 8 + q] = hs[q];
                Ald[rl * 8 + q] = hd[q];
            }
        }
    }
    __syncthreads();
    #pragma unroll
    for (int k = 0; k < 2; ++k) {
        int idx = tid + k * 256;
        int rl = idx >> 3, q = idx & 7;
        int row = bm + rl;
        if (row < M) {
            alpha_s[(size_t)row * H_HEADS + q] = Als[idx];
            alpha_d[(size_t)row * H_HEADS + q] = Ald[idx];
        }
    }
}

// ---------------------------------------------------------------------------
// Layer-2 persistent GEMM (A bf16, K=256). Block owns one col-half (128 cols);
// the col-half's FULL-K B (64 KB) is staged into LDS ONCE, then the block
// grid-strides over 64-row tiles with ZERO barriers in the stream loop ->
// A-loads pipeline with fine-grained vmcnt. Fused fp8 + alpha epilogue.
// ---------------------------------------------------------------------------
__global__ __launch_bounds__(256) void gemm2_persist(const short* __restrict__ z1b,
    const short* __restrict__ Bf2, unsigned char* __restrict__ h8,
    const float* __restrict__ a_s, const float* __restrict__ a_d,
    float* __restrict__ alpha_s, float* __restrict__ alpha_d, int M)
{
    __shared__ short Bs[32768];              // 64 KB = col-half of Wf2, all K

    const int tid  = threadIdx.x;
    const int w    = tid >> 6;
    const int lane = tid & 63;
    const int quad = lane >> 4;
    const int ml   = lane & 15;
    const int ch   = blockIdx.x & 1;         // col half: cols ch*128..+127
    const int bid2 = blockIdx.x >> 1;
    const int bstr = gridDim.x >> 1;

    // ---- stage half-B: 8 K-steps x 4096 shorts ----
    #pragma unroll
    for (int s = 0; s < 8; ++s) {
        const short* gbase = Bf2 + (size_t)(s * 16 + ch * 8) * 512;
        #pragma unroll
        for (int sw = 0; sw < 2; ++sw) {
            int i = sw * 2048 + tid * 8;
            gl2lds16(gbase + i, &Bs[s * 4096 + i]);
        }
    }
    __syncthreads();                         // DMA complete; no more barriers

    float as_v[8], ad_v[8];
    #pragma unroll
    for (int nb = 0; nb < 8; ++nb) {
        as_v[nb] = a_s[(ch * 8 + nb) * 16 + ml];
        ad_v[nb] = a_d[(ch * 8 + nb) * 16 + ml];
    }

    const int nt = (M + 63) >> 6;
    for (int rt = bid2; rt < nt; rt += bstr) {
        const int rowA = rt * 64 + w * 16 + ml;
        const int rowL = rowA < M ? rowA : M - 1;
        const short* arow = z1b + (size_t)rowL * HC;

        bf16x8 av[8];
        #pragma unroll
        for (int s = 0; s < 8; ++s)
            av[s] = *(const bf16x8*)(arow + s * 32 + quad * 8);

        f32x4 acc[8];
        #pragma unroll
        for (int nb = 0; nb < 8; ++nb) acc[nb] = (f32x4){0.f, 0.f, 0.f, 0.f};

        #pragma unroll
        for (int s = 0; s < 8; ++s) {
            const short* bsrc = &Bs[s * 4096 + lane * 8];
            #pragma unroll
            for (int nb = 0; nb < 8; ++nb) {
                bf16x8 bfr = *(const bf16x8*)(bsrc + nb * 512);
                acc[nb] = __builtin_amdgcn_mfma_f32_16x16x32_bf16(av[s], bfr, acc[nb], 0, 0, 0);
            }
        }

        #pragma unroll
        for (int r = 0; r < 4; ++r) {
            const int row = rt * 64 + w * 16 + quad * 4 + r;
            float hs[4], hd[4];
            #pragma unroll
            for (int q = 0; q < 4; ++q) {
                hs[q] = acc[2 * q][r] * as_v[2 * q] + acc[2 * q + 1][r] * as_v[2 * q + 1];
                hd[q] = acc[2 * q][r] * ad_v[2 * q] + acc[2 * q + 1][r] * ad_v[2 * q + 1];
            }
            #pragma unroll
            for (int off = 1; off < 16; off <<= 1) {
                #pragma unroll
                for (int q = 0; q < 4; ++q) {
                    hs[q] += __shfl_xor(hs[q], off);
                    hd[q] += __shfl_xor(hd[q], off);
                }
            }
            if (row < M) {
                unsigned char* hrow = h8 + (size_t)row * HC;
                #pragma unroll
                for (int i = 0; i < 4; ++i) {
                    int pk = __builtin_amdgcn_cvt_pk_fp8_f32(acc[2 * i][r], acc[2 * i + 1][r], 0, false);
                    hrow[(ch * 8 + 2 * i) * 16 + ml]     = (unsigned char)(pk & 0xFF);
                    hrow[(ch * 8 + 2 * i + 1) * 16 + ml] = (unsigned char)((pk >> 8) & 0xFF);
                }
                if (ml == 0) {
                    #pragma unroll
                    for (int q = 0; q < 4; ++q) {
                        alpha_s[(size_t)row * H_HEADS + ch * 4 + q] = hs[q];
                        alpha_d[(size_t)row * H_HEADS + ch * 4 + q] = hd[q];
                    }
                }
            }
        }
    }
}

// ---------------------------------------------------------------------------
// Per-edge softmax weights (fp16): w[p,h] = exp(leaky(alpha_s[src]+alpha_d[dst]))
// ---------------------------------------------------------------------------
__global__ __launch_bounds__(256) void wcalc_kernel(const int2* __restrict__ es,
    const float* __restrict__ alpha_s, const float* __restrict__ alpha_d,
    _Float16* __restrict__ wq, int P)
{
    int p = blockIdx.x * 256 + threadIdx.x;
    if (p >= P) return;
    int2 sd = es[p];
    const float4* as = (const float4*)(alpha_s + (size_t)sd.x * H_HEADS);
    const float4* ad = (const float4*)(alpha_d + (size_t)sd.y * H_HEADS);
    float4 s0 = as[0], s1 = as[1], d0 = ad[0], d1 = ad[1];
    float e[8] = {s0.x + d0.x, s0.y + d0.y, s0.z + d0.z, s0.w + d0.w,
                  s1.x + d1.x, s1.y + d1.y, s1.z + d1.z, s1.w + d1.w};
    h16x8 o;
    #pragma unroll
    for (int h = 0; h < 8; ++h) {
        float v = e[h] > 0.f ? e[h] : NEG_SLOPE * e[h];
        o[h] = (_Float16)__expf(v);
    }
    *(h16x8*)(wq + (size_t)p * H_HEADS) = o;
}

// ---------------------------------------------------------------------------
// CSR build
// ---------------------------------------------------------------------------
__global__ void zero_int(int* __restrict__ p, int n)
{
    int i = blockIdx.x * 256 + threadIdx.x;
    if (i < n) p[i] = 0;
}

__global__ void hist_kernel(const int* __restrict__ ei, int E, int N,
                            int* __restrict__ cnt)
{
    int e = blockIdx.x * 256 + threadIdx.x;
    if (e < E) atomicAdd(&cnt[ei[E + e]], 1);
    else if (e < E + N) atomicAdd(&cnt[e - E], 1);
}

__global__ __launch_bounds__(256) void scan_sum(const int* __restrict__ cnt, int n,
                                                int* __restrict__ chunk_sum)
{
    __shared__ int lds[256];
    int b = blockIdx.x, t = threadIdx.x;
    int base = b * 1024 + t * 4;
    int s = 0;
    #pragma unroll
    for (int j = 0; j < 4; ++j) { int i = base + j; if (i < n) s += cnt[i]; }
    lds[t] = s; __syncthreads();
    for (int off = 128; off > 0; off >>= 1) {
        if (t < off) lds[t] += lds[t + off];
        __syncthreads();
    }
    if (t == 0) chunk_sum[b] = lds[0];
}

__global__ void scan_top(const int* __restrict__ chunk_sum, int nch,
                         int* __restrict__ chunk_off, int* __restrict__ row_ptr,
                         int n_nodes)
{
    int t = threadIdx.x;
    int v = (t < nch) ? chunk_sum[t] : 0;
    int inc = v;
    #pragma unroll
    for (int off = 1; off < 64; off <<= 1) {
        int u = __shfl_up(inc, off);
        if (t >= off) inc += u;
    }
    if (t < nch) chunk_off[t] = inc - v;
    if (t == 63) row_ptr[n_nodes] = inc;
}

__global__ __launch_bounds__(256) void scan_local(const int* __restrict__ cnt, int n,
    const int* __restrict__ chunk_off, int* __restrict__ row_ptr)
{
    __shared__ int lds[256];
    int b = blockIdx.x, t = threadIdx.x;
    int base = b * 1024 + t * 4;
    int v[4]; int s = 0;
    #pragma unroll
    for (int j = 0; j < 4; ++j) { int i = base + j; v[j] = (i < n) ? cnt[i] : 0; s += v[j]; }
    lds[t] = s; __syncthreads();
    for (int off = 1; off < 256; off <<= 1) {
        int u = (t >= off) ? lds[t - off] : 0;
        __syncthreads();
        lds[t] += u;
        __syncthreads();
    }
    int run = lds[t] - s + chunk_off[b];
    #pragma unroll
    for (int j = 0; j < 4; ++j) {
        int i = base + j;
        if (i < n) row_ptr[i] = run;
        run += v[j];
    }
}

// ---- 2-pass bucket scatter: bucket = dst>>6; bucket bases come from row_ptr ----
__global__ void scatter1_kernel(const int* __restrict__ ei, int E, int N,
    const int* __restrict__ row_ptr, int* __restrict__ fill1, int2* __restrict__ tmp)
{
    int e = blockIdx.x * 256 + threadIdx.x;
    int src, dst;
    if (e < E)          { src = ei[e]; dst = ei[E + e]; }
    else if (e < E + N) { src = dst = e - E; }
    else return;
    int b = dst >> 6;
    int pos = row_ptr[b << 6] + atomicAdd(&fill1[b], 1);
    tmp[pos] = make_int2(src, dst);
}

__global__ __launch_bounds__(256) void scatter2_kernel(const int2* __restrict__ tmp,
    const int* __restrict__ row_ptr, int N, int2* __restrict__ es)
{
    __shared__ int f[64];
    int b = blockIdx.x;
    int n0 = b * 64;
    int n1 = n0 + 64; if (n1 > N) n1 = N;
    if (threadIdx.x < 64) f[threadIdx.x] = 0;
    __syncthreads();
    int p0 = row_ptr[n0], p1 = row_ptr[n1];
    for (int p = p0 + threadIdx.x; p < p1; p += 256) {
        int2 sd = tmp[p];
        int pos = row_ptr[sd.y] + atomicAdd(&f[sd.y & 63], 1);
        es[pos] = sd;
    }
}

// ---------------------------------------------------------------------------
// Layer-1 aggregation: one wave per dst node, lane owns 4 channels (fp8 dword
// gather), x8 unrolled edge loop. z written bf16 (layer-2 GEMM A input).
// ---------------------------------------------------------------------------
__global__ __launch_bounds__(256) void agg1_kernel(const unsigned* __restrict__ h8,
    const _Float16* __restrict__ wq, const int* __restrict__ row_ptr,
    const int2* __restrict__ es, const float* __restrict__ bias,
    short* __restrict__ z_bf, int N)
{
    const int l = threadIdx.x & 63;
    const int i = blockIdx.x * 4 + (threadIdx.x >> 6);
    if (i >= N) return;
    const int hh = l >> 3;
    const int beg = row_ptr[i], end = row_ptr[i + 1];
    f32x4 acc = {0.f, 0.f, 0.f, 0.f};
    float dsum = 0.f;
    int p = beg;
    for (; p + 7 < end; p += 8) {
        int s[8]; float w[8]; unsigned hv[8];
        #pragma unroll
        for (int u = 0; u < 8; ++u) s[u] = es[p + u].x;
        #pragma unroll
        for (int u = 0; u < 8; ++u) w[u] = (float)wq[(size_t)(p + u) * 8 + hh];
        #pragma unroll
        for (int u = 0; u < 8; ++u) hv[u] = h8[(size_t)s[u] * 64 + l];
        #pragma unroll
        for (int u = 0; u < 8; ++u) {
            f32x2 lo = __builtin_amdgcn_cvt_pk_f32_fp8(hv[u], false);
            f32x2 hi = __builtin_amdgcn_cvt_pk_f32_fp8(hv[u], true);
            acc[0] = fmaf(w[u], lo[0], acc[0]);
            acc[1] = fmaf(w[u], lo[1], acc[1]);
            acc[2] = fmaf(w[u], hi[0], acc[2]);
            acc[3] = fmaf(w[u], hi[1], acc[3]);
            dsum += w[u];
        }
    }
    for (; p < end; ++p) {
        int s0 = es[p].x;
        float w0 = (float)wq[(size_t)p * 8 + hh];
        unsigned hv = h8[(size_t)s0 * 64 + l];
        f32x2 lo = __builtin_amdgcn_cvt_pk_f32_fp8(hv, false);
        f32x2 hi = __builtin_amdgcn_cvt_pk_f32_fp8(hv, true);
        acc[0] = fmaf(w0, lo[0], acc[0]);
        acc[1] = fmaf(w0, lo[1], acc[1]);
        acc[2] = fmaf(w0, hi[0], acc[2]);
        acc[3] = fmaf(w0, hi[1], acc[3]);
        dsum += w0;
    }
    float inv = 1.f / (dsum + 1e-16f);
    s16x4 pk;
    #pragma unroll
    for (int j = 0; j < 4; ++j) {
        float z = acc[j] * inv + bias[4 * l + j];
        pk[j] = f2bf(z > 0.f ? z : 0.f);
    }
    *(s16x4*)(z_bf + (size_t)i * HC + 4 * l) = pk;
}

// ---------------------------------------------------------------------------
// Layer-2 aggregation fused with head-mean + b2 + Wp dot + sigmoid.
// ---------------------------------------------------------------------------
__global__ __launch_bounds__(256) void agg2_kernel(const unsigned* __restrict__ h8,
    const _Float16* __restrict__ wq, const int* __restrict__ row_ptr,
    const int2* __restrict__ es, const float* __restrict__ b2,
    const float* __restrict__ Wp, const float* __restrict__ bp,
    float* __restrict__ out, int N)
{
    const int l = threadIdx.x & 63;
    const int i = blockIdx.x * 4 + (threadIdx.x >> 6);
    if (i >= N) return;
    const int hh = l >> 3;
    const int beg = row_ptr[i], end = row_ptr[i + 1];
    f32x4 acc = {0.f, 0.f, 0.f, 0.f};
    float dsum = 0.f;
    int p = beg;
    for (; p + 7 < end; p += 8) {
        int s[8]; float w[8]; unsigned hv[8];
        #pragma unroll
        for (int u = 0; u < 8; ++u) s[u] = es[p + u].x;
        #pragma unroll
        for (int u = 0; u < 8; ++u) w[u] = (float)wq[(size_t)(p + u) * 8 + hh];
        #pragma unroll
        for (int u = 0; u < 8; ++u) hv[u] = h8[(size_t)s[u] * 64 + l];
        #pragma unroll
        for (int u = 0; u < 8; ++u) {
            f32x2 lo = __builtin_amdgcn_cvt_pk_f32_fp8(hv[u], false);
            f32x2 hi = __builtin_amdgcn_cvt_pk_f32_fp8(hv[u], true);
            acc[0] = fmaf(w[u], lo[0], acc[0]);
            acc[1] = fmaf(w[u], lo[1], acc[1]);
            acc[2] = fmaf(w[u], hi[0], acc[2]);
            acc[3] = fmaf(w[u], hi[1], acc[3]);
            dsum += w[u];
        }
    }
    for (; p < end; ++p) {
        int s0 = es[p].x;
        float w0 = (float)wq[(size_t)p * 8 + hh];
        unsigned hv = h8[(size_t)s0 * 64 + l];
        f32x2 lo = __builtin_amdgcn_cvt_pk_f32_fp8(hv, false);
        f32x2 hi = __builtin_amdgcn_cvt_pk_f32_fp8(hv, true);
        acc[0] = fmaf(w0, lo[0], acc[0]);
        acc[1] = fmaf(w0, lo[1], acc[1]);
        acc[2] = fmaf(w0, hi[0], acc[2]);
        acc[3] = fmaf(w0, hi[1], acc[3]);
        dsum += w0;
    }
    float inv = 1.f / (dsum + 1e-16f);
    int cc = (4 * l) & 31;
    float partial = 0.f;
    #pragma unroll
    for (int j = 0; j < 4; ++j) partial = fmaf(acc[j] * inv, Wp[cc + j], partial);
    if (l < 8) {
        #pragma unroll
        for (int j = 0; j < 4; ++j) partial = fmaf(8.f * b2[4 * l + j], Wp[4 * l + j], partial);
    }
    #pragma unroll
    for (int off = 32; off > 0; off >>= 1) partial += __shfl_xor(partial, off);
    if (l == 0) out[i] = 1.f / (1.f + __expf(-(0.125f * partial + bp[0])));
}

// ---------------------------------------------------------------------------
extern "C" void kernel_launch(void* const* d_in, const int* in_sizes, int n_in,
                              void* d_out, int out_size, void* d_ws, size_t ws_size,
                              hipStream_t stream)
{
    const int*   ei  = (const int*)d_in[0];
    const float* x   = (const float*)d_in[1];
    const float* W1  = (const float*)d_in[2];
    const float* as1 = (const float*)d_in[3];
    const float* ad1 = (const float*)d_in[4];
    const float* b1  = (const float*)d_in[5];
    const float* W2  = (const float*)d_in[6];
    const float* as2 = (const float*)d_in[7];
    const float* ad2 = (const float*)d_in[8];
    const float* b2  = (const float*)d_in[9];
    const float* Wp  = (const float*)d_in[10];
    const float* bp  = (const float*)d_in[11];
    float* out = (float*)d_out;

    const int E   = in_sizes[0] / 2;
    const int N   = in_sizes[1] / F_IN;
    const int ET  = E + N;
    const int NBK = (N + 63) / 64;

    // workspace layout
    float*         asb = (float*)d_ws;                           // N*8 f32
    float*         adb = asb + (size_t)N * H_HEADS;              // N*8 f32
    unsigned char* h8  = (unsigned char*)(adb + (size_t)N * H_HEADS); // N*256 fp8
    short*         z1b = (short*)(h8 + (size_t)N * HC);          // N*256 bf16
    short*         Wf1 = z1b + (size_t)N * HC;                   // 512*256 bf16
    short*         Wf2 = Wf1 + (size_t)F_IN * HC;                // 256*256 bf16
    _Float16*      wq  = (_Float16*)(Wf2 + (size_t)HC * HC);     // (E+N)*8 fp16
    int2*          es  = (int2*)(wq + (size_t)ET * H_HEADS);     // ET int2
    int2*          tmp = es + ET;                                // ET int2
    int* cnt       = (int*)(tmp + ET);                           // N
    int* fill1     = cnt + N;                                    // NBK
    int* row_ptr   = fill1 + NBK;                                // N+1
    int* chunk_off = row_ptr + N + 1;                            // 64
    int* chunk_sum = chunk_off + 64;                             // 64

    const int NCH = (N + 1023) / 1024;
    const int MB  = (N + 63) / 64;
    const int NB4 = (N + 3) / 4;

    // ---- CSR build ----
    zero_int<<<(N + NBK + 255) / 256, 256, 0, stream>>>(cnt, N + NBK);
    hist_kernel<<<(ET + 255) / 256, 256, 0, stream>>>(ei, E, N, cnt);
    scan_sum<<<NCH, 256, 0, stream>>>(cnt, N, chunk_sum);
    scan_top<<<1, 64, 0, stream>>>(chunk_sum, NCH, chunk_off, row_ptr, N);
    scan_local<<<NCH, 256, 0, stream>>>(cnt, N, chunk_off, row_ptr);
    scatter1_kernel<<<(ET + 255) / 256, 256, 0, stream>>>(ei, E, N, row_ptr, fill1, tmp);
    scatter2_kernel<<<NBK, 256, 0, stream>>>(tmp, row_ptr, N, es);

    // ---- W repack ----
    wfrag_kernel<<<(F_IN * HC + 255) / 256, 256, 0, stream>>>(W1, Wf1, F_IN);
    wfrag_kernel<<<(HC * HC + 255) / 256, 256, 0, stream>>>(W2, Wf2, HC);

    // ---- Layer 1 ----
    gemm1_mfma<<<MB, 256, 0, stream>>>(x, Wf1, h8, as1, ad1, asb, adb, N);
    wcalc_kernel<<<(ET + 255) / 256, 256, 0, stream>>>(es, asb, adb, wq, ET);
    agg1_kernel<<<NB4, 256, 0, stream>>>((const unsigned*)h8, wq, row_ptr, es, b1, z1b, N);

    // ---- Layer 2 ----
    gemm2_persist<<<512, 256, 0, stream>>>(z1b, Wf2, h8, as2, ad2, asb, adb, N);
    wcalc_kernel<<<(ET + 255) / 256, 256, 0, stream>>>(es, asb, adb, wq, ET);
    agg2_kernel<<<NB4, 256, 0, stream>>>((const unsigned*)h8, wq, row_ptr, es, b2, Wp, bp, out, N);
}

// Round 7
// 431.591 us; speedup vs baseline: 1.4650x; 1.4650x over previous
//
#include <hip/hip_runtime.h>
#include <math.h>

#define H_HEADS 8
#define C_DIM   32
#define HC      256
#define F_IN    512
#define NEG_SLOPE 0.2f

typedef __attribute__((ext_vector_type(8))) short    bf16x8;
typedef __attribute__((ext_vector_type(4))) short    s16x4;
typedef __attribute__((ext_vector_type(4))) float    f32x4;
typedef __attribute__((ext_vector_type(2))) float    f32x2;
typedef __attribute__((ext_vector_type(8))) _Float16 h16x8;

__device__ __forceinline__ short f2bf(float f) {
    union { float f; unsigned u; } v; v.f = f;
    unsigned r = v.u + 0x7FFF + ((v.u >> 16) & 1);   // RNE
    return (short)(r >> 16);
}

__device__ __forceinline__ void gl2lds16(const short* g, short* l) {
    __builtin_amdgcn_global_load_lds(
        (const __attribute__((address_space(1))) void*)g,
        (__attribute__((address_space(3))) void*)l, 16, 0, 0);
}

// ---------------------------------------------------------------------------
// Repack W [K,256] fp32 -> MFMA B-frag-ordered bf16 (16 KB per K-step of 32).
// ---------------------------------------------------------------------------
__global__ void wfrag_kernel(const float* __restrict__ W, short* __restrict__ Wf, int K)
{
    int tid = blockIdx.x * 256 + threadIdx.x;
    if (tid >= K * HC) return;
    int j  = tid & 7;
    int l  = (tid >> 3) & 63;
    int nb = (tid >> 9) & 15;
    int s  = tid >> 13;
    int k  = s * 32 + (l >> 4) * 8 + j;
    int n  = nb * 16 + (l & 15);
    Wf[tid] = f2bf(W[(size_t)k * HC + n]);
}

// ---------------------------------------------------------------------------
// Layer-1 MFMA GEMM (A fp32, K=512). 64-row x 256-col tile, 4 waves.
// B LDS double-buffer (2x16KB); A prefetched two steps deep. Fused epilogue:
// h8 (fp8 e4m3) + per-head alpha dots. (No forced occupancy bound: R6's
// __launch_bounds__(256,4) likely spilled the epilogue.)
// ---------------------------------------------------------------------------
__global__ __launch_bounds__(256) void gemm1_mfma(const float* __restrict__ A32,
    const short* __restrict__ Bf, unsigned char* __restrict__ h8,
    const float* __restrict__ a_s, const float* __restrict__ a_d,
    float* __restrict__ alpha_s, float* __restrict__ alpha_d, int M)
{
    __shared__ short Bs[2][8192];            // 32 KB

    const int tid  = threadIdx.x;
    const int w    = tid >> 6;
    const int lane = tid & 63;
    const int quad = lane >> 4;
    const int ml   = lane & 15;
    const int bm   = blockIdx.x * 64;

    const int rowA = bm + w * 16 + ml;
    const int rowL = rowA < M ? rowA : M - 1;

    f32x4 acc[16];
    #pragma unroll
    for (int nb = 0; nb < 16; ++nb) acc[nb] = (f32x4){0.f, 0.f, 0.f, 0.f};

    const int nsteps = F_IN >> 5;            // 16

    {   // stage B step 0
        const short* g = Bf + (size_t)w * 2048 + lane * 8;
        short* l = &Bs[0][w * 2048];
        #pragma unroll
        for (int c = 0; c < 4; ++c) gl2lds16(g + c * 512, l + c * 512);
    }

    // 2-deep A prefetch
    const float* abase = A32 + (size_t)rowL * F_IN + quad * 8;
    float4 pa[2][2];
    pa[0][0] = *(const float4*)(abase);
    pa[0][1] = *(const float4*)(abase + 4);
    pa[1][0] = *(const float4*)(abase + 32);
    pa[1][1] = *(const float4*)(abase + 36);

    for (int s = 0; s < nsteps; ++s) {
        __syncthreads();

        if (s + 1 < nsteps) {
            const short* g = Bf + (size_t)(s + 1) * 8192 + w * 2048 + lane * 8;
            short* l = &Bs[(s + 1) & 1][w * 2048];
            #pragma unroll
            for (int c = 0; c < 4; ++c) gl2lds16(g + c * 512, l + c * 512);
        }

        bf16x8 af;
        {
            float4 q0 = pa[s & 1][0], q1 = pa[s & 1][1];
            af[0] = f2bf(q0.x); af[1] = f2bf(q0.y); af[2] = f2bf(q0.z); af[3] = f2bf(q0.w);
            af[4] = f2bf(q1.x); af[5] = f2bf(q1.y); af[6] = f2bf(q1.z); af[7] = f2bf(q1.w);
        }
        if (s + 2 < nsteps) {
            pa[s & 1][0] = *(const float4*)(abase + (s + 2) * 32);
            pa[s & 1][1] = *(const float4*)(abase + (s + 2) * 32 + 4);
        }

        const short* bsrc = &Bs[s & 1][lane * 8];
        #pragma unroll
        for (int nb = 0; nb < 16; ++nb) {
            bf16x8 bfr = *(const bf16x8*)(bsrc + nb * 512);
            acc[nb] = __builtin_amdgcn_mfma_f32_16x16x32_bf16(af, bfr, acc[nb], 0, 0, 0);
        }
    }

    // ---- epilogue: fp8 store + fused per-head alpha dots ----
    float as_v[16], ad_v[16];
    #pragma unroll
    for (int nb = 0; nb < 16; ++nb) {
        as_v[nb] = a_s[nb * 16 + ml];
        ad_v[nb] = a_d[nb * 16 + ml];
    }

    __syncthreads();                          // B buffers dead; alias for alpha
    float* Als = (float*)&Bs[0][0];           // 512 f32
    float* Ald = Als + 512;                   // 512 f32

    #pragma unroll
    for (int r = 0; r < 4; ++r) {
        const int rl  = w * 16 + quad * 4 + r;
        const int row = bm + rl;

        if (row < M) {
            unsigned char* hrow = h8 + (size_t)row * HC;
            #pragma unroll
            for (int i = 0; i < 8; ++i) {
                int pk = __builtin_amdgcn_cvt_pk_fp8_f32(acc[2 * i][r], acc[2 * i + 1][r], 0, false);
                hrow[(2 * i) * 16 + ml]     = (unsigned char)(pk & 0xFF);
                hrow[(2 * i + 1) * 16 + ml] = (unsigned char)((pk >> 8) & 0xFF);
            }
        }

        float hs[8], hd[8];
        #pragma unroll
        for (int q = 0; q < 8; ++q) {
            hs[q] = acc[2 * q][r] * as_v[2 * q] + acc[2 * q + 1][r] * as_v[2 * q + 1];
            hd[q] = acc[2 * q][r] * ad_v[2 * q] + acc[2 * q + 1][r] * ad_v[2 * q + 1];
        }
        #pragma unroll
        for (int off = 1; off < 16; off <<= 1) {
            #pragma unroll
            for (int q = 0; q < 8; ++q) {
                hs[q] += __shfl_xor(hs[q], off);
                hd[q] += __shfl_xor(hd[q], off);
            }
        }
        if (ml == 0) {
            #pragma unroll
            for (int q = 0; q < 8; ++q) {
                Als[rl * 8 + q] = hs[q];
                Ald[rl * 8 + q] = hd[q];
            }
        }
    }
    __syncthreads();
    #pragma unroll
    for (int k = 0; k < 2; ++k) {
        int idx = tid + k * 256;
        int rl = idx >> 3, q = idx & 7;
        int row = bm + rl;
        if (row < M) {
            alpha_s[(size_t)row * H_HEADS + q] = Als[idx];
            alpha_d[(size_t)row * H_HEADS + q] = Ald[idx];
        }
    }
}

// ---------------------------------------------------------------------------
// Layer-2 persistent GEMM (A bf16, K=256). Col-half B (64 KB) staged in LDS
// once; barrier-free row-tile stream loop. Fused fp8 + alpha epilogue.
// ---------------------------------------------------------------------------
__global__ __launch_bounds__(256) void gemm2_persist(const short* __restrict__ z1b,
    const short* __restrict__ Bf2, unsigned char* __restrict__ h8,
    const float* __restrict__ a_s, const float* __restrict__ a_d,
    float* __restrict__ alpha_s, float* __restrict__ alpha_d, int M)
{
    __shared__ short Bs[32768];              // 64 KB

    const int tid  = threadIdx.x;
    const int w    = tid >> 6;
    const int lane = tid & 63;
    const int quad = lane >> 4;
    const int ml   = lane & 15;
    const int ch   = blockIdx.x & 1;
    const int bid2 = blockIdx.x >> 1;
    const int bstr = gridDim.x >> 1;

    #pragma unroll
    for (int s = 0; s < 8; ++s) {
        const short* gbase = Bf2 + (size_t)(s * 16 + ch * 8) * 512;
        #pragma unroll
        for (int sw = 0; sw < 2; ++sw) {
            int i = sw * 2048 + tid * 8;
            gl2lds16(gbase + i, &Bs[s * 4096 + i]);
        }
    }
    __syncthreads();

    float as_v[8], ad_v[8];
    #pragma unroll
    for (int nb = 0; nb < 8; ++nb) {
        as_v[nb] = a_s[(ch * 8 + nb) * 16 + ml];
        ad_v[nb] = a_d[(ch * 8 + nb) * 16 + ml];
    }

    const int nt = (M + 63) >> 6;
    for (int rt = bid2; rt < nt; rt += bstr) {
        const int rowA = rt * 64 + w * 16 + ml;
        const int rowL = rowA < M ? rowA : M - 1;
        const short* arow = z1b + (size_t)rowL * HC;

        bf16x8 av[8];
        #pragma unroll
        for (int s = 0; s < 8; ++s)
            av[s] = *(const bf16x8*)(arow + s * 32 + quad * 8);

        f32x4 acc[8];
        #pragma unroll
        for (int nb = 0; nb < 8; ++nb) acc[nb] = (f32x4){0.f, 0.f, 0.f, 0.f};

        #pragma unroll
        for (int s = 0; s < 8; ++s) {
            const short* bsrc = &Bs[s * 4096 + lane * 8];
            #pragma unroll
            for (int nb = 0; nb < 8; ++nb) {
                bf16x8 bfr = *(const bf16x8*)(bsrc + nb * 512);
                acc[nb] = __builtin_amdgcn_mfma_f32_16x16x32_bf16(av[s], bfr, acc[nb], 0, 0, 0);
            }
        }

        #pragma unroll
        for (int r = 0; r < 4; ++r) {
            const int row = rt * 64 + w * 16 + quad * 4 + r;
            float hs[4], hd[4];
            #pragma unroll
            for (int q = 0; q < 4; ++q) {
                hs[q] = acc[2 * q][r] * as_v[2 * q] + acc[2 * q + 1][r] * as_v[2 * q + 1];
                hd[q] = acc[2 * q][r] * ad_v[2 * q] + acc[2 * q + 1][r] * ad_v[2 * q + 1];
            }
            #pragma unroll
            for (int off = 1; off < 16; off <<= 1) {
                #pragma unroll
                for (int q = 0; q < 4; ++q) {
                    hs[q] += __shfl_xor(hs[q], off);
                    hd[q] += __shfl_xor(hd[q], off);
                }
            }
            if (row < M) {
                unsigned char* hrow = h8 + (size_t)row * HC;
                #pragma unroll
                for (int i = 0; i < 4; ++i) {
                    int pk = __builtin_amdgcn_cvt_pk_fp8_f32(acc[2 * i][r], acc[2 * i + 1][r], 0, false);
                    hrow[(ch * 8 + 2 * i) * 16 + ml]     = (unsigned char)(pk & 0xFF);
                    hrow[(ch * 8 + 2 * i + 1) * 16 + ml] = (unsigned char)((pk >> 8) & 0xFF);
                }
                if (ml == 0) {
                    #pragma unroll
                    for (int q = 0; q < 4; ++q) {
                        alpha_s[(size_t)row * H_HEADS + ch * 4 + q] = hs[q];
                        alpha_d[(size_t)row * H_HEADS + ch * 4 + q] = hd[q];
                    }
                }
            }
        }
    }
}

// ---------------------------------------------------------------------------
// Per-edge softmax weights (fp16)
// ---------------------------------------------------------------------------
__global__ __launch_bounds__(256) void wcalc_kernel(const int2* __restrict__ es,
    const float* __restrict__ alpha_s, const float* __restrict__ alpha_d,
    _Float16* __restrict__ wq, int P)
{
    int p = blockIdx.x * 256 + threadIdx.x;
    if (p >= P) return;
    int2 sd = es[p];
    const float4* as = (const float4*)(alpha_s + (size_t)sd.x * H_HEADS);
    const float4* ad = (const float4*)(alpha_d + (size_t)sd.y * H_HEADS);
    float4 s0 = as[0], s1 = as[1], d0 = ad[0], d1 = ad[1];
    float e[8] = {s0.x + d0.x, s0.y + d0.y, s0.z + d0.z, s0.w + d0.w,
                  s1.x + d1.x, s1.y + d1.y, s1.z + d1.z, s1.w + d1.w};
    h16x8 o;
    #pragma unroll
    for (int h = 0; h < 8; ++h) {
        float v = e[h] > 0.f ? e[h] : NEG_SLOPE * e[h];
        o[h] = (_Float16)__expf(v);
    }
    *(h16x8*)(wq + (size_t)p * H_HEADS) = o;
}

// ---------------------------------------------------------------------------
// CSR build
// ---------------------------------------------------------------------------
__global__ void zero_int(int* __restrict__ p, int n)
{
    int i = blockIdx.x * 256 + threadIdx.x;
    if (i < n) p[i] = 0;
}

__global__ void hist_kernel(const int* __restrict__ ei, int E, int N,
                            int* __restrict__ cnt)
{
    int e = blockIdx.x * 256 + threadIdx.x;
    if (e < E) atomicAdd(&cnt[ei[E + e]], 1);
    else if (e < E + N) atomicAdd(&cnt[e - E], 1);
}

__global__ __launch_bounds__(256) void scan_sum(const int* __restrict__ cnt, int n,
                                                int* __restrict__ chunk_sum)
{
    __shared__ int lds[256];
    int b = blockIdx.x, t = threadIdx.x;
    int base = b * 1024 + t * 4;
    int s = 0;
    #pragma unroll
    for (int j = 0; j < 4; ++j) { int i = base + j; if (i < n) s += cnt[i]; }
    lds[t] = s; __syncthreads();
    for (int off = 128; off > 0; off >>= 1) {
        if (t < off) lds[t] += lds[t + off];
        __syncthreads();
    }
    if (t == 0) chunk_sum[b] = lds[0];
}

__global__ void scan_top(const int* __restrict__ chunk_sum, int nch,
                         int* __restrict__ chunk_off, int* __restrict__ row_ptr,
                         int n_nodes)
{
    int t = threadIdx.x;
    int v = (t < nch) ? chunk_sum[t] : 0;
    int inc = v;
    #pragma unroll
    for (int off = 1; off < 64; off <<= 1) {
        int u = __shfl_up(inc, off);
        if (t >= off) inc += u;
    }
    if (t < nch) chunk_off[t] = inc - v;
    if (t == 63) row_ptr[n_nodes] = inc;
}

__global__ __launch_bounds__(256) void scan_local(const int* __restrict__ cnt, int n,
    const int* __restrict__ chunk_off, int* __restrict__ row_ptr)
{
    __shared__ int lds[256];
    int b = blockIdx.x, t = threadIdx.x;
    int base = b * 1024 + t * 4;
    int v[4]; int s = 0;
    #pragma unroll
    for (int j = 0; j < 4; ++j) { int i = base + j; v[j] = (i < n) ? cnt[i] : 0; s += v[j]; }
    lds[t] = s; __syncthreads();
    for (int off = 1; off < 256; off <<= 1) {
        int u = (t >= off) ? lds[t - off] : 0;
        __syncthreads();
        lds[t] += u;
        __syncthreads();
    }
    int run = lds[t] - s + chunk_off[b];
    #pragma unroll
    for (int j = 0; j < 4; ++j) {
        int i = base + j;
        if (i < n) row_ptr[i] = run;
        run += v[j];
    }
}

// ---------------------------------------------------------------------------
// Pass-1 scatter, block-level radix: T=8192 edges/block. LDS per-bucket
// histogram -> ONE global atomic per (block,bucket) -> LDS-cursor scatter.
// Global atomic count ~80k (vs 800k direct), contention <=104 per counter.
// ---------------------------------------------------------------------------
#define SC_T 8192
__global__ __launch_bounds__(256) void scatter1_kernel(const int* __restrict__ ei,
    int E, int ET, int NBK, const int* __restrict__ row_ptr,
    int* __restrict__ fill1, int2* __restrict__ tmp)
{
    __shared__ int hist[1024];   // per-bucket count, then absolute cursor
    const int t  = threadIdx.x;
    const int e0 = blockIdx.x * SC_T;

    for (int b = t; b < NBK; b += 256) hist[b] = 0;
    __syncthreads();

    // phase A: histogram buckets
    #pragma unroll 4
    for (int k = 0; k < SC_T / 256; ++k) {
        int e = e0 + k * 256 + t;
        if (e < ET) {
            int dst = (e < E) ? ei[E + e] : e - E;
            atomicAdd(&hist[dst >> 6], 1);
        }
    }
    __syncthreads();

    // phase B: reserve global ranges; hist[b] becomes absolute write cursor
    for (int b = t; b < NBK; b += 256) {
        int c = hist[b];
        int base = 0;
        if (c > 0) base = row_ptr[b << 6] + atomicAdd(&fill1[b], c);
        __syncthreads();       // uniform: all threads iterate same #times
        hist[b] = base;
        __syncthreads();
    }
    __syncthreads();

    // phase C: scatter through LDS cursors
    #pragma unroll 4
    for (int k = 0; k < SC_T / 256; ++k) {
        int e = e0 + k * 256 + t;
        if (e < ET) {
            int src, dst;
            if (e < E) { src = ei[e]; dst = ei[E + e]; }
            else       { src = dst = e - E; }
            int pos = atomicAdd(&hist[dst >> 6], 1);
            tmp[pos] = make_int2(src, dst);
        }
    }
}

__global__ __launch_bounds__(256) void scatter2_kernel(const int2* __restrict__ tmp,
    const int* __restrict__ row_ptr, int N, int2* __restrict__ es)
{
    __shared__ int f[64];
    int b = blockIdx.x;
    int n0 = b * 64;
    int n1 = n0 + 64; if (n1 > N) n1 = N;
    if (threadIdx.x < 64) f[threadIdx.x] = 0;
    __syncthreads();
    int p0 = row_ptr[n0], p1 = row_ptr[n1];
    for (int p = p0 + threadIdx.x; p < p1; p += 256) {
        int2 sd = tmp[p];
        int pos = row_ptr[sd.y] + atomicAdd(&f[sd.y & 63], 1);
        es[pos] = sd;
    }
}

// ---------------------------------------------------------------------------
// Layer-1 aggregation: wave per dst node, lane owns 4 channels (fp8 dword
// gather), x8 unrolled. z written bf16.
// ---------------------------------------------------------------------------
__global__ __launch_bounds__(256) void agg1_kernel(const unsigned* __restrict__ h8,
    const _Float16* __restrict__ wq, const int* __restrict__ row_ptr,
    const int2* __restrict__ es, const float* __restrict__ bias,
    short* __restrict__ z_bf, int N)
{
    const int l = threadIdx.x & 63;
    const int i = blockIdx.x * 4 + (threadIdx.x >> 6);
    if (i >= N) return;
    const int hh = l >> 3;
    const int beg = row_ptr[i], end = row_ptr[i + 1];
    f32x4 acc = {0.f, 0.f, 0.f, 0.f};
    float dsum = 0.f;
    int p = beg;
    for (; p + 7 < end; p += 8) {
        int s[8]; float w[8]; unsigned hv[8];
        #pragma unroll
        for (int u = 0; u < 8; ++u) s[u] = es[p + u].x;
        #pragma unroll
        for (int u = 0; u < 8; ++u) w[u] = (float)wq[(size_t)(p + u) * 8 + hh];
        #pragma unroll
        for (int u = 0; u < 8; ++u) hv[u] = h8[(size_t)s[u] * 64 + l];
        #pragma unroll
        for (int u = 0; u < 8; ++u) {
            f32x2 lo = __builtin_amdgcn_cvt_pk_f32_fp8(hv[u], false);
            f32x2 hi = __builtin_amdgcn_cvt_pk_f32_fp8(hv[u], true);
            acc[0] = fmaf(w[u], lo[0], acc[0]);
            acc[1] = fmaf(w[u], lo[1], acc[1]);
            acc[2] = fmaf(w[u], hi[0], acc[2]);
            acc[3] = fmaf(w[u], hi[1], acc[3]);
            dsum += w[u];
        }
    }
    for (; p < end; ++p) {
        int s0 = es[p].x;
        float w0 = (float)wq[(size_t)p * 8 + hh];
        unsigned hv = h8[(size_t)s0 * 64 + l];
        f32x2 lo = __builtin_amdgcn_cvt_pk_f32_fp8(hv, false);
        f32x2 hi = __builtin_amdgcn_cvt_pk_f32_fp8(hv, true);
        acc[0] = fmaf(w0, lo[0], acc[0]);
        acc[1] = fmaf(w0, lo[1], acc[1]);
        acc[2] = fmaf(w0, hi[0], acc[2]);
        acc[3] = fmaf(w0, hi[1], acc[3]);
        dsum += w0;
    }
    float inv = 1.f / (dsum + 1e-16f);
    s16x4 pk;
    #pragma unroll
    for (int j = 0; j < 4; ++j) {
        float z = acc[j] * inv + bias[4 * l + j];
        pk[j] = f2bf(z > 0.f ? z : 0.f);
    }
    *(s16x4*)(z_bf + (size_t)i * HC + 4 * l) = pk;
}

// ---------------------------------------------------------------------------
// Layer-2 aggregation fused with head-mean + b2 + Wp dot + sigmoid.
// ---------------------------------------------------------------------------
__global__ __launch_bounds__(256) void agg2_kernel(const unsigned* __restrict__ h8,
    const _Float16* __restrict__ wq, const int* __restrict__ row_ptr,
    const int2* __restrict__ es, const float* __restrict__ b2,
    const float* __restrict__ Wp, const float* __restrict__ bp,
    float* __restrict__ out, int N)
{
    const int l = threadIdx.x & 63;
    const int i = blockIdx.x * 4 + (threadIdx.x >> 6);
    if (i >= N) return;
    const int hh = l >> 3;
    const int beg = row_ptr[i], end = row_ptr[i + 1];
    f32x4 acc = {0.f, 0.f, 0.f, 0.f};
    float dsum = 0.f;
    int p = beg;
    for (; p + 7 < end; p += 8) {
        int s[8]; float w[8]; unsigned hv[8];
        #pragma unroll
        for (int u = 0; u < 8; ++u) s[u] = es[p + u].x;
        #pragma unroll
        for (int u = 0; u < 8; ++u) w[u] = (float)wq[(size_t)(p + u) * 8 + hh];
        #pragma unroll
        for (int u = 0; u < 8; ++u) hv[u] = h8[(size_t)s[u] * 64 + l];
        #pragma unroll
        for (int u = 0; u < 8; ++u) {
            f32x2 lo = __builtin_amdgcn_cvt_pk_f32_fp8(hv[u], false);
            f32x2 hi = __builtin_amdgcn_cvt_pk_f32_fp8(hv[u], true);
            acc[0] = fmaf(w[u], lo[0], acc[0]);
            acc[1] = fmaf(w[u], lo[1], acc[1]);
            acc[2] = fmaf(w[u], hi[0], acc[2]);
            acc[3] = fmaf(w[u], hi[1], acc[3]);
            dsum += w[u];
        }
    }
    for (; p < end; ++p) {
        int s0 = es[p].x;
        float w0 = (float)wq[(size_t)p * 8 + hh];
        unsigned hv = h8[(size_t)s0 * 64 + l];
        f32x2 lo = __builtin_amdgcn_cvt_pk_f32_fp8(hv, false);
        f32x2 hi = __builtin_amdgcn_cvt_pk_f32_fp8(hv, true);
        acc[0] = fmaf(w0, lo[0], acc[0]);
        acc[1] = fmaf(w0, lo[1], acc[1]);
        acc[2] = fmaf(w0, hi[0], acc[2]);
        acc[3] = fmaf(w0, hi[1], acc[3]);
        dsum += w0;
    }
    float inv = 1.f / (dsum + 1e-16f);
    int cc = (4 * l) & 31;
    float partial = 0.f;
    #pragma unroll
    for (int j = 0; j < 4; ++j) partial = fmaf(acc[j] * inv, Wp[cc + j], partial);
    if (l < 8) {
        #pragma unroll
        for (int j = 0; j < 4; ++j) partial = fmaf(8.f * b2[4 * l + j], Wp[4 * l + j], partial);
    }
    #pragma unroll
    for (int off = 32; off > 0; off >>= 1) partial += __shfl_xor(partial, off);
    if (l == 0) out[i] = 1.f / (1.f + __expf(-(0.125f * partial + bp[0])));
}

// ---------------------------------------------------------------------------
extern "C" void kernel_launch(void* const* d_in, const int* in_sizes, int n_in,
                              void* d_out, int out_size, void* d_ws, size_t ws_size,
                              hipStream_t stream)
{
    const int*   ei  = (const int*)d_in[0];
    const float* x   = (const float*)d_in[1];
    const float* W1  = (const float*)d_in[2];
    const float* as1 = (const float*)d_in[3];
    const float* ad1 = (const float*)d_in[4];
    const float* b1  = (const float*)d_in[5];
    const float* W2  = (const float*)d_in[6];
    const float* as2 = (const float*)d_in[7];
    const float* ad2 = (const float*)d_in[8];
    const float* b2  = (const float*)d_in[9];
    const float* Wp  = (const float*)d_in[10];
    const float* bp  = (const float*)d_in[11];
    float* out = (float*)d_out;

    const int E   = in_sizes[0] / 2;
    const int N   = in_sizes[1] / F_IN;
    const int ET  = E + N;
    const int NBK = (N + 63) / 64;

    // workspace layout
    float*         asb = (float*)d_ws;                           // N*8 f32
    float*         adb = asb + (size_t)N * H_HEADS;              // N*8 f32
    unsigned char* h8  = (unsigned char*)(adb + (size_t)N * H_HEADS); // N*256 fp8
    short*         z1b = (short*)(h8 + (size_t)N * HC);          // N*256 bf16
    short*         Wf1 = z1b + (size_t)N * HC;                   // 512*256 bf16
    short*         Wf2 = Wf1 + (size_t)F_IN * HC;                // 256*256 bf16
    _Float16*      wq  = (_Float16*)(Wf2 + (size_t)HC * HC);     // (E+N)*8 fp16
    int2*          es  = (int2*)(wq + (size_t)ET * H_HEADS);     // ET int2
    int2*          tmp = es + ET;                                // ET int2
    int* cnt       = (int*)(tmp + ET);                           // N
    int* fill1     = cnt + N;                                    // NBK
    int* row_ptr   = fill1 + NBK;                                // N+1
    int* chunk_off = row_ptr + N + 1;                            // 64
    int* chunk_sum = chunk_off + 64;                             // 64

    const int NCH = (N + 1023) / 1024;
    const int MB  = (N + 63) / 64;
    const int NB4 = (N + 3) / 4;
    const int NB1 = (ET + SC_T - 1) / SC_T;

    // ---- CSR build ----
    zero_int<<<(N + NBK + 255) / 256, 256, 0, stream>>>(cnt, N + NBK);
    hist_kernel<<<(ET + 255) / 256, 256, 0, stream>>>(ei, E, N, cnt);
    scan_sum<<<NCH, 256, 0, stream>>>(cnt, N, chunk_sum);
    scan_top<<<1, 64, 0, stream>>>(chunk_sum, NCH, chunk_off, row_ptr, N);
    scan_local<<<NCH, 256, 0, stream>>>(cnt, N, chunk_off, row_ptr);
    scatter1_kernel<<<NB1, 256, 0, stream>>>(ei, E, ET, NBK, row_ptr, fill1, tmp);
    scatter2_kernel<<<NBK, 256, 0, stream>>>(tmp, row_ptr, N, es);

    // ---- W repack ----
    wfrag_kernel<<<(F_IN * HC + 255) / 256, 256, 0, stream>>>(W1, Wf1, F_IN);
    wfrag_kernel<<<(HC * HC + 255) / 256, 256, 0, stream>>>(W2, Wf2, HC);

    // ---- Layer 1 ----
    gemm1_mfma<<<MB, 256, 0, stream>>>(x, Wf1, h8, as1, ad1, asb, adb, N);
    wcalc_kernel<<<(ET + 255) / 256, 256, 0, stream>>>(es, asb, adb, wq, ET);
    agg1_kernel<<<NB4, 256, 0, stream>>>((const unsigned*)h8, wq, row_ptr, es, b1, z1b, N);

    // ---- Layer 2 ----
    gemm2_persist<<<512, 256, 0, stream>>>(z1b, Wf2, h8, as2, ad2, asb, adb, N);
    wcalc_kernel<<<(ET + 255) / 256, 256, 0, stream>>>(es, asb, adb, wq, ET);
    agg2_kernel<<<NB4, 256, 0, stream>>>((const unsigned*)h8, wq, row_ptr, es, b2, Wp, bp, out, N);
}